// Round 1
// baseline (5177.960 us; speedup 1.0000x reference)
//
#include <hip/hip_runtime.h>

// Problem constants
#define B_   32
#define T_   48
#define S_   30
#define INF  16
#define H1   128
#define OUTF 64
#define H    3840     // GRU hidden (= GRU input here)
#define G3   11520    // 3*H
#define K_   3840
#define M_   1536     // B_*T_
#define KS   8        // split-K factor for recurrent GEMM

// ---------------- kernel 0: zero h ----------------
__global__ void k_zero(float* __restrict__ p, int n) {
  int i = blockIdx.x * 256 + threadIdx.x;
  if (i < n) p[i] = 0.0f;
}

// ---------------- kernel 1: FC(16->128) + ReLU -> xi [T][B][S*128] ----------------
__global__ __launch_bounds__(128) void k_fc_relu(const float* __restrict__ x,
                                                 const float* __restrict__ fc_w,
                                                 const float* __restrict__ fc_b,
                                                 float* __restrict__ xi) {
  int idx = blockIdx.x;              // (b*T_+t)*S_+s
  int s  = idx % S_;
  int bt = idx / S_;
  int t  = bt % T_;
  int b  = bt / T_;
  int hh = threadIdx.x;              // 0..127
  const float* xr = x + (size_t)idx * INF;
  const float* w  = fc_w + (size_t)hh * INF;
  float acc = fc_b[hh];
  #pragma unroll
  for (int i = 0; i < INF; ++i) acc = fmaf(xr[i], w[i], acc);
  acc = fmaxf(acc, 0.0f);
  xi[((size_t)t * B_ + b) * H + s * H1 + hh] = acc;
}

// ---------------- kernel 2: C[M][N] = A[M][K] @ Bw[N][K]^T + bias ----------------
#define BM 128
#define BN 128
#define BK 32
__global__ __launch_bounds__(256) void k_gemm_bias(const float* __restrict__ A,
                                                   const float* __restrict__ Bw,
                                                   const float* __restrict__ bias,
                                                   float* __restrict__ C,
                                                   int M, int N, int K) {
  __shared__ float As[BK][BM + 4];
  __shared__ float Bs[BK][BN + 4];
  const int tid = threadIdx.x;
  const int tx = tid & 15;           // n-quad (8 cols each)
  const int ty = tid >> 4;           // m-quad (8 rows each)
  const int m0 = blockIdx.y * BM;
  const int n0 = blockIdx.x * BN;
  float acc[8][8] = {};
  for (int k0 = 0; k0 < K; k0 += BK) {
    float4 av[4], bv[4];
    #pragma unroll
    for (int l = 0; l < 4; ++l) {
      int f = tid + l * 256;         // 0..1023
      int row = f >> 3, kq = f & 7;  // 128 rows x 8 float4
      av[l] = *(const float4*)(A  + (size_t)(m0 + row) * K + k0 + kq * 4);
      bv[l] = *(const float4*)(Bw + (size_t)(n0 + row) * K + k0 + kq * 4);
    }
    __syncthreads();                 // previous iter's compute done before overwrite
    #pragma unroll
    for (int l = 0; l < 4; ++l) {
      int f = tid + l * 256;
      int row = f >> 3, kq = f & 7;
      As[kq * 4 + 0][row] = av[l].x; As[kq * 4 + 1][row] = av[l].y;
      As[kq * 4 + 2][row] = av[l].z; As[kq * 4 + 3][row] = av[l].w;
      Bs[kq * 4 + 0][row] = bv[l].x; Bs[kq * 4 + 1][row] = bv[l].y;
      Bs[kq * 4 + 2][row] = bv[l].z; Bs[kq * 4 + 3][row] = bv[l].w;
    }
    __syncthreads();
    #pragma unroll
    for (int kk = 0; kk < BK; ++kk) {
      float a[8], b[8];
      *(float4*)&a[0] = *(const float4*)&As[kk][ty * 8];
      *(float4*)&a[4] = *(const float4*)&As[kk][ty * 8 + 4];
      *(float4*)&b[0] = *(const float4*)&Bs[kk][tx * 8];
      *(float4*)&b[4] = *(const float4*)&Bs[kk][tx * 8 + 4];
      #pragma unroll
      for (int i = 0; i < 8; ++i)
        #pragma unroll
        for (int j = 0; j < 8; ++j)
          acc[i][j] = fmaf(a[i], b[j], acc[i][j]);
    }
  }
  #pragma unroll
  for (int i = 0; i < 8; ++i) {
    int m = m0 + ty * 8 + i;
    #pragma unroll
    for (int j = 0; j < 8; j += 4) {
      int n = n0 + tx * 8 + j;
      float4 v;
      v.x = acc[i][j + 0] + bias[n + 0];
      v.y = acc[i][j + 1] + bias[n + 1];
      v.z = acc[i][j + 2] + bias[n + 2];
      v.w = acc[i][j + 3] + bias[n + 3];
      *(float4*)(C + (size_t)m * N + n) = v;
    }
  }
}

// ---------------- kernel 3: partial gh = h @ W_hh^T (split-K, split-N) ----------------
// grid: (KS, H/32); block 256. part layout: [KS][3][B_][H]
__global__ __launch_bounds__(256) void k_gh_partial(const float* __restrict__ h,
                                                    const float* __restrict__ W_hh,
                                                    float* __restrict__ part) {
  __shared__ float hsT[32][33];        // [kk][b]
  __shared__ float Ws[3][32][36];      // [sec][kk][j] (36-pad keeps f4 16B-aligned)
  const int tid = threadIdx.x;
  const int ks = blockIdx.x;
  const int j0 = blockIdx.y * 32;
  const int kb = ks * (K_ / KS);       // 480-wide K strip
  const int tx = tid & 7;              // j-quad (4 cols)
  const int ty = tid >> 3;             // b (0..31)
  const int lr = tid >> 3;             // staging row 0..31
  const int lk = tid & 7;              // staging float4 idx
  float acc[3][4] = {};
  for (int kc = kb; kc < kb + (K_ / KS); kc += 32) {
    float4 hv = *(const float4*)(h + (size_t)lr * H + kc + lk * 4);
    float4 wv[3];
    #pragma unroll
    for (int s = 0; s < 3; ++s)
      wv[s] = *(const float4*)(W_hh + ((size_t)s * H + j0 + lr) * K_ + kc + lk * 4);
    __syncthreads();
    hsT[lk * 4 + 0][lr] = hv.x; hsT[lk * 4 + 1][lr] = hv.y;
    hsT[lk * 4 + 2][lr] = hv.z; hsT[lk * 4 + 3][lr] = hv.w;
    #pragma unroll
    for (int s = 0; s < 3; ++s) {
      Ws[s][lk * 4 + 0][lr] = wv[s].x; Ws[s][lk * 4 + 1][lr] = wv[s].y;
      Ws[s][lk * 4 + 2][lr] = wv[s].z; Ws[s][lk * 4 + 3][lr] = wv[s].w;
    }
    __syncthreads();
    #pragma unroll
    for (int kk = 0; kk < 32; ++kk) {
      float hb = hsT[kk][ty];
      #pragma unroll
      for (int s = 0; s < 3; ++s) {
        float4 w4 = *(const float4*)&Ws[s][kk][tx * 4];
        acc[s][0] = fmaf(hb, w4.x, acc[s][0]);
        acc[s][1] = fmaf(hb, w4.y, acc[s][1]);
        acc[s][2] = fmaf(hb, w4.z, acc[s][2]);
        acc[s][3] = fmaf(hb, w4.w, acc[s][3]);
      }
    }
  }
  #pragma unroll
  for (int s = 0; s < 3; ++s) {
    float4 v = make_float4(acc[s][0], acc[s][1], acc[s][2], acc[s][3]);
    *(float4*)(part + (((size_t)ks * 3 + s) * B_ + ty) * H + j0 + tx * 4) = v;
  }
}

// ---------------- kernel 4: reduce partials + GRU gates, h update ----------------
__global__ __launch_bounds__(256) void k_gates(const float* __restrict__ part,
                                               const float* __restrict__ gx_t,
                                               const float* __restrict__ b_hh,
                                               float* __restrict__ h) {
  int idx = blockIdx.x * 256 + threadIdx.x;     // 0..B_*H-1
  if (idx >= B_ * H) return;
  int b = idx / H, j = idx % H;
  float ghr = 0.f, ghz = 0.f, ghn = 0.f;
  #pragma unroll
  for (int ks = 0; ks < KS; ++ks) {
    const float* p = part + (((size_t)ks * 3) * B_ + b) * H + j;
    ghr += p[0];
    ghz += p[(size_t)B_ * H];
    ghn += p[2 * (size_t)B_ * H];
  }
  ghr += b_hh[j];
  ghz += b_hh[H + j];
  ghn += b_hh[2 * H + j];
  float gxr = gx_t[(size_t)b * G3 + j];
  float gxz = gx_t[(size_t)b * G3 + H + j];
  float gxn = gx_t[(size_t)b * G3 + 2 * H + j];
  float r = 1.0f / (1.0f + __expf(-(gxr + ghr)));
  float z = 1.0f / (1.0f + __expf(-(gxz + ghz)));
  float n = tanhf(gxn + r * ghn);
  float hv = h[idx];
  h[idx] = (1.0f - z) * n + z * hv;
}

// ---------------- kernel 5: out = relu(h).reshape(B,S,128) @ fc2_w^T + fc2_b ----------------
__global__ __launch_bounds__(64) void k_fc2(const float* __restrict__ h,
                                            const float* __restrict__ fc2_w,
                                            const float* __restrict__ fc2_b,
                                            float* __restrict__ out) {
  int bs = blockIdx.x;                // b*30+s
  int b = bs / S_, s = bs % S_;
  int o = threadIdx.x;                // 0..63
  __shared__ float e[H1];
  const float* hr = h + (size_t)b * H + s * H1;
  e[o]      = fmaxf(hr[o], 0.0f);
  e[o + 64] = fmaxf(hr[o + 64], 0.0f);
  __syncthreads();
  float acc = fc2_b[o];
  const float* w = fc2_w + (size_t)o * H1;
  #pragma unroll 8
  for (int c = 0; c < H1; ++c) acc = fmaf(e[c], w[c], acc);
  out[(size_t)bs * OUTF + o] = acc;
}

// ---------------- host-side launcher ----------------
extern "C" void kernel_launch(void* const* d_in, const int* in_sizes, int n_in,
                              void* d_out, int out_size, void* d_ws, size_t ws_size,
                              hipStream_t stream) {
  const float* x     = (const float*)d_in[0];
  // d_in[1] = adj (unused, WoGCN ablation)
  const float* fc_w  = (const float*)d_in[2];
  const float* fc_b  = (const float*)d_in[3];
  const float* W_ih  = (const float*)d_in[4];
  const float* W_hh  = (const float*)d_in[5];
  const float* b_ih  = (const float*)d_in[6];
  const float* b_hh  = (const float*)d_in[7];
  const float* fc2_w = (const float*)d_in[8];
  const float* fc2_b = (const float*)d_in[9];
  float* out = (float*)d_out;

  // workspace layout (floats): xi | gx | part | h  = ~106.7 MB
  float* xi   = (float*)d_ws;
  float* gx   = xi + (size_t)M_ * H;          // + 5,898,240
  float* part = gx + (size_t)M_ * G3;         // +17,694,720
  float* h    = part + (size_t)KS * 3 * B_ * H; // + 2,949,120

  // h0 = 0
  k_zero<<<(B_ * H + 255) / 256, 256, 0, stream>>>(h, B_ * H);

  // FC + ReLU -> xi [T][B][3840]
  k_fc_relu<<<B_ * T_ * S_, 128, 0, stream>>>(x, fc_w, fc_b, xi);

  // gx[t][b][g] = xi @ W_ih^T + b_ih   (one big GEMM, M=1536,N=11520,K=3840)
  k_gemm_bias<<<dim3(G3 / BN, M_ / BM), 256, 0, stream>>>(xi, W_ih, b_ih, gx, M_, G3, K_);

  // recurrent steps
  for (int t = 0; t < T_; ++t) {
    k_gh_partial<<<dim3(KS, H / 32), 256, 0, stream>>>(h, W_hh, part);
    k_gates<<<(B_ * H + 255) / 256, 256, 0, stream>>>(part, gx + (size_t)t * B_ * G3, b_hh, h);
  }

  // final FC2
  k_fc2<<<B_ * S_, 64, 0, stream>>>(h, fc2_w, fc2_b, out);
}

// Round 2
// 4773.771 us; speedup vs baseline: 1.0847x; 1.0847x over previous
//
#include <hip/hip_runtime.h>

// Problem constants
#define B_   32
#define T_   48
#define S_   30
#define INF  16
#define H1   128
#define OUTF 64
#define H    3840     // GRU hidden (= GRU input here)
#define G3   11520    // 3*H
#define K_   3840
#define M_   1536     // B_*T_

// ---------------- kernel 0: zero h ----------------
__global__ void k_zero(float* __restrict__ p, int n) {
  int i = blockIdx.x * 256 + threadIdx.x;
  if (i < n) p[i] = 0.0f;
}

// ---------------- kernel 1: FC(16->128) + ReLU -> xi [T][B][S*128] ----------------
__global__ __launch_bounds__(128) void k_fc_relu(const float* __restrict__ x,
                                                 const float* __restrict__ fc_w,
                                                 const float* __restrict__ fc_b,
                                                 float* __restrict__ xi) {
  int idx = blockIdx.x;              // (b*T_+t)*S_+s
  int s  = idx % S_;
  int bt = idx / S_;
  int t  = bt % T_;
  int b  = bt / T_;
  int hh = threadIdx.x;              // 0..127
  const float* xr = x + (size_t)idx * INF;
  const float* w  = fc_w + (size_t)hh * INF;
  float acc = fc_b[hh];
  #pragma unroll
  for (int i = 0; i < INF; ++i) acc = fmaf(xr[i], w[i], acc);
  acc = fmaxf(acc, 0.0f);
  xi[((size_t)t * B_ + b) * H + s * H1 + hh] = acc;
}

// ---------------- kernel 2: C[M][N] = A[M][K] @ Bw[N][K]^T + bias ----------------
#define BM 128
#define BN 128
#define BK 32
__global__ __launch_bounds__(256) void k_gemm_bias(const float* __restrict__ A,
                                                   const float* __restrict__ Bw,
                                                   const float* __restrict__ bias,
                                                   float* __restrict__ C,
                                                   int M, int N, int K) {
  __shared__ float As[BK][BM + 4];
  __shared__ float Bs[BK][BN + 4];
  const int tid = threadIdx.x;
  const int tx = tid & 15;           // n-group
  const int ty = tid >> 4;           // m-group
  const int m0 = blockIdx.y * BM;
  const int n0 = blockIdx.x * BN;
  float acc[8][8] = {};
  for (int k0 = 0; k0 < K; k0 += BK) {
    float4 av[4], bv[4];
    #pragma unroll
    for (int l = 0; l < 4; ++l) {
      int f = tid + l * 256;         // 0..1023
      int row = f >> 3, kq = f & 7;  // 128 rows x 8 float4
      av[l] = *(const float4*)(A  + (size_t)(m0 + row) * K + k0 + kq * 4);
      bv[l] = *(const float4*)(Bw + (size_t)(n0 + row) * K + k0 + kq * 4);
    }
    __syncthreads();                 // previous iter's compute done before overwrite
    #pragma unroll
    for (int l = 0; l < 4; ++l) {
      int f = tid + l * 256;
      int row = f >> 3, kq = f & 7;
      As[kq * 4 + 0][row] = av[l].x; As[kq * 4 + 1][row] = av[l].y;
      As[kq * 4 + 2][row] = av[l].z; As[kq * 4 + 3][row] = av[l].w;
      Bs[kq * 4 + 0][row] = bv[l].x; Bs[kq * 4 + 1][row] = bv[l].y;
      Bs[kq * 4 + 2][row] = bv[l].z; Bs[kq * 4 + 3][row] = bv[l].w;
    }
    __syncthreads();
    #pragma unroll
    for (int kk = 0; kk < BK; ++kk) {
      float a[8], b[8];
      // split fragments: rows ty*4..ty*4+3 and 64+ty*4.. ; cols tx*4.. and 64+tx*4..
      *(float4*)&a[0] = *(const float4*)&As[kk][ty * 4];
      *(float4*)&a[4] = *(const float4*)&As[kk][64 + ty * 4];
      *(float4*)&b[0] = *(const float4*)&Bs[kk][tx * 4];
      *(float4*)&b[4] = *(const float4*)&Bs[kk][64 + tx * 4];
      #pragma unroll
      for (int i = 0; i < 8; ++i)
        #pragma unroll
        for (int j = 0; j < 8; ++j)
          acc[i][j] = fmaf(a[i], b[j], acc[i][j]);
    }
  }
  #pragma unroll
  for (int i = 0; i < 8; ++i) {
    int m = m0 + (i < 4 ? ty * 4 + i : 64 + ty * 4 + (i - 4));
    #pragma unroll
    for (int jb = 0; jb < 2; ++jb) {
      int n = n0 + (jb == 0 ? tx * 4 : 64 + tx * 4);
      float4 v;
      v.x = acc[i][jb * 4 + 0] + bias[n + 0];
      v.y = acc[i][jb * 4 + 1] + bias[n + 1];
      v.z = acc[i][jb * 4 + 2] + bias[n + 2];
      v.w = acc[i][jb * 4 + 3] + bias[n + 3];
      *(float4*)(C + (size_t)m * N + n) = v;
    }
  }
}

// ---------------- kernel 3: partial gh = h @ W_hh^T (split-K, split-G) ----------------
// grid: (KSP, G3/GT); block 256. part layout: [KSP][B_][G3]
#define GT   256
#define KSP  15
#define KSTRIP 256   // K_/KSP
__global__ __launch_bounds__(256) void k_gh(const float* __restrict__ h,
                                            const float* __restrict__ W_hh,
                                            float* __restrict__ part) {
  __shared__ float hsT[32][36];        // [kk][b]
  __shared__ float Ws[32][GT + 4];     // [kk][g]
  const int tid = threadIdx.x;
  const int ks = blockIdx.x;
  const int g0 = blockIdx.y * GT;
  const int kb = ks * KSTRIP;
  const int tx = tid & 31;             // g-oct (8 cols)
  const int ty = tid >> 5;             // b-quad (4 rows)
  const int hb = tid >> 3;             // h stage row 0..31
  const int hk = tid & 7;              // h stage f4 idx
  float acc[4][8] = {};
  float4 wv[8], hv;
  // prefetch chunk 0
  #pragma unroll
  for (int l = 0; l < 8; ++l) {
    int f = tid + l * 256;
    int gr = f >> 3, kq = f & 7;
    wv[l] = *(const float4*)(W_hh + (size_t)(g0 + gr) * K_ + kb + kq * 4);
  }
  hv = *(const float4*)(h + (size_t)hb * H + kb + hk * 4);
  for (int c = 0; c < KSTRIP / 32; ++c) {
    __syncthreads();                   // prior compute done before overwrite
    #pragma unroll
    for (int l = 0; l < 8; ++l) {
      int f = tid + l * 256;
      int gr = f >> 3, kq = f & 7;
      Ws[kq * 4 + 0][gr] = wv[l].x; Ws[kq * 4 + 1][gr] = wv[l].y;
      Ws[kq * 4 + 2][gr] = wv[l].z; Ws[kq * 4 + 3][gr] = wv[l].w;
    }
    hsT[hk * 4 + 0][hb] = hv.x; hsT[hk * 4 + 1][hb] = hv.y;
    hsT[hk * 4 + 2][hb] = hv.z; hsT[hk * 4 + 3][hb] = hv.w;
    __syncthreads();
    if (c + 1 < KSTRIP / 32) {         // prefetch next chunk (overlaps compute)
      int kc = kb + (c + 1) * 32;
      #pragma unroll
      for (int l = 0; l < 8; ++l) {
        int f = tid + l * 256;
        int gr = f >> 3, kq = f & 7;
        wv[l] = *(const float4*)(W_hh + (size_t)(g0 + gr) * K_ + kc + kq * 4);
      }
      hv = *(const float4*)(h + (size_t)hb * H + kc + hk * 4);
    }
    #pragma unroll
    for (int kk = 0; kk < 32; ++kk) {
      float h4[4], w8[8];
      *(float4*)&h4[0] = *(const float4*)&hsT[kk][ty * 4];
      *(float4*)&w8[0] = *(const float4*)&Ws[kk][tx * 8];
      *(float4*)&w8[4] = *(const float4*)&Ws[kk][tx * 8 + 4];
      #pragma unroll
      for (int i = 0; i < 4; ++i)
        #pragma unroll
        for (int j = 0; j < 8; ++j)
          acc[i][j] = fmaf(h4[i], w8[j], acc[i][j]);
    }
  }
  #pragma unroll
  for (int i = 0; i < 4; ++i) {
    float* dst = part + ((size_t)ks * B_ + ty * 4 + i) * G3 + g0 + tx * 8;
    *(float4*)dst       = make_float4(acc[i][0], acc[i][1], acc[i][2], acc[i][3]);
    *(float4*)(dst + 4) = make_float4(acc[i][4], acc[i][5], acc[i][6], acc[i][7]);
  }
}

// ---------------- kernel 4: reduce partials + GRU gates, h update ----------------
__global__ __launch_bounds__(256) void k_gates(const float* __restrict__ part,
                                               const float* __restrict__ gx_t,
                                               const float* __restrict__ b_hh,
                                               float* __restrict__ h) {
  int v = blockIdx.x * 256 + threadIdx.x;       // 0 .. B_*H/4-1
  int b = v / (H / 4);
  int j = (v - b * (H / 4)) * 4;
  float r[4] = {}, z[4] = {}, n[4] = {};
  for (int ks = 0; ks < KSP; ++ks) {
    const float* base = part + ((size_t)ks * B_ + b) * G3;
    float4 pr = *(const float4*)(base + j);
    float4 pz = *(const float4*)(base + H + j);
    float4 pn = *(const float4*)(base + 2 * H + j);
    r[0] += pr.x; r[1] += pr.y; r[2] += pr.z; r[3] += pr.w;
    z[0] += pz.x; z[1] += pz.y; z[2] += pz.z; z[3] += pz.w;
    n[0] += pn.x; n[1] += pn.y; n[2] += pn.z; n[3] += pn.w;
  }
  float4 bhr = *(const float4*)(b_hh + j);
  float4 bhz = *(const float4*)(b_hh + H + j);
  float4 bhn = *(const float4*)(b_hh + 2 * H + j);
  const float* gxp = gx_t + (size_t)b * G3;
  float4 gxr = *(const float4*)(gxp + j);
  float4 gxz = *(const float4*)(gxp + H + j);
  float4 gxn = *(const float4*)(gxp + 2 * H + j);
  float* hp = h + (size_t)b * H + j;
  float4 hv = *(const float4*)hp;
  float ghr[4] = { r[0] + bhr.x, r[1] + bhr.y, r[2] + bhr.z, r[3] + bhr.w };
  float ghz[4] = { z[0] + bhz.x, z[1] + bhz.y, z[2] + bhz.z, z[3] + bhz.w };
  float ghn[4] = { n[0] + bhn.x, n[1] + bhn.y, n[2] + bhn.z, n[3] + bhn.w };
  float gx_r[4] = { gxr.x, gxr.y, gxr.z, gxr.w };
  float gx_z[4] = { gxz.x, gxz.y, gxz.z, gxz.w };
  float gx_n[4] = { gxn.x, gxn.y, gxn.z, gxn.w };
  float hva[4] = { hv.x, hv.y, hv.z, hv.w };
  float out[4];
  #pragma unroll
  for (int q = 0; q < 4; ++q) {
    float rr = 1.0f / (1.0f + __expf(-(gx_r[q] + ghr[q])));
    float zz = 1.0f / (1.0f + __expf(-(gx_z[q] + ghz[q])));
    float nn = tanhf(gx_n[q] + rr * ghn[q]);
    out[q] = (1.0f - zz) * nn + zz * hva[q];
  }
  *(float4*)hp = make_float4(out[0], out[1], out[2], out[3]);
}

// ---------------- kernel 5: out = relu(h).reshape(B,S,128) @ fc2_w^T + fc2_b ----------------
__global__ __launch_bounds__(64) void k_fc2(const float* __restrict__ h,
                                            const float* __restrict__ fc2_w,
                                            const float* __restrict__ fc2_b,
                                            float* __restrict__ out) {
  int bs = blockIdx.x;                // b*30+s
  int b = bs / S_, s = bs % S_;
  int o = threadIdx.x;                // 0..63
  __shared__ float e[H1];
  const float* hr = h + (size_t)b * H + s * H1;
  e[o]      = fmaxf(hr[o], 0.0f);
  e[o + 64] = fmaxf(hr[o + 64], 0.0f);
  __syncthreads();
  float acc = fc2_b[o];
  const float* w = fc2_w + (size_t)o * H1;
  #pragma unroll 8
  for (int c = 0; c < H1; ++c) acc = fmaf(e[c], w[c], acc);
  out[(size_t)bs * OUTF + o] = acc;
}

// ---------------- host-side launcher ----------------
extern "C" void kernel_launch(void* const* d_in, const int* in_sizes, int n_in,
                              void* d_out, int out_size, void* d_ws, size_t ws_size,
                              hipStream_t stream) {
  const float* x     = (const float*)d_in[0];
  // d_in[1] = adj (unused, WoGCN ablation)
  const float* fc_w  = (const float*)d_in[2];
  const float* fc_b  = (const float*)d_in[3];
  const float* W_ih  = (const float*)d_in[4];
  const float* W_hh  = (const float*)d_in[5];
  const float* b_ih  = (const float*)d_in[6];
  const float* b_hh  = (const float*)d_in[7];
  const float* fc2_w = (const float*)d_in[8];
  const float* fc2_b = (const float*)d_in[9];
  float* out = (float*)d_out;

  // workspace layout (floats): [xi | part(aliased)] | gx | h  = ~94.9 MB
  // xi (5,898,240 f) is dead after the big GEMM; part (15*32*11520 = 5,529,600 f)
  // aliases it. gx follows, then h.
  float* xi   = (float*)d_ws;
  float* part = (float*)d_ws;                   // alias: used only after gemm consumed xi
  float* gx   = xi + (size_t)M_ * H;            // + 5,898,240
  float* h    = gx + (size_t)M_ * G3;           // +17,694,720

  // h0 = 0
  k_zero<<<(B_ * H + 255) / 256, 256, 0, stream>>>(h, B_ * H);

  // FC + ReLU -> xi [T][B][3840]
  k_fc_relu<<<B_ * T_ * S_, 128, 0, stream>>>(x, fc_w, fc_b, xi);

  // gx[t][b][g] = xi @ W_ih^T + b_ih   (one big GEMM, M=1536,N=11520,K=3840)
  k_gemm_bias<<<dim3(G3 / BN, M_ / BM), 256, 0, stream>>>(xi, W_ih, b_ih, gx, M_, G3, K_);

  // recurrent steps
  for (int t = 0; t < T_; ++t) {
    k_gh<<<dim3(KSP, G3 / GT), 256, 0, stream>>>(h, W_hh, part);
    k_gates<<<(B_ * H / 4 + 255) / 256, 256, 0, stream>>>(part, gx + (size_t)t * B_ * G3, b_hh, h);
  }

  // final FC2
  k_fc2<<<B_ * S_, 64, 0, stream>>>(h, fc2_w, fc2_b, out);
}